// Round 1
// baseline (1735.485 us; speedup 1.0000x reference)
//
#include <hip/hip_runtime.h>
#include <cstddef>

// Problem constants
#define TT   32
#define NN   256
#define NLL  16
#define HH   256
#define CONDD 64
#define NEE  8
#define H3   768   // 3*H
// Output row: [A, W, w_new, v, h(256), a_probs(16), p_probs(32)] = 308
#define OW   308

__device__ __forceinline__ float sigm(float x)     { return 1.f / (1.f + __expf(-x)); }
__device__ __forceinline__ float tanhfast(float x) { return 1.f - 2.f / (__expf(2.f * x) + 1.f); }

// ---------------------------------------------------------------------------
// Generic sub-block transpose: out[c][r] = in[r][c0+c], out is (Cout, R)
// ---------------------------------------------------------------------------
__global__ void k_transpose_sub(const float* __restrict__ in, float* __restrict__ out,
                                int R, int Cin, int c0, int Cout) {
    int idx = blockIdx.x * 256 + threadIdx.x;
    if (idx >= R * Cout) return;
    int r = idx / Cout, c = idx % Cout;
    out[(size_t)c * R + r] = in[(size_t)r * Cin + c0 + c];
}

// ---------------------------------------------------------------------------
// Per-token input projections. For each vocab token v (64):
//   gif[v][col] = embed[v] . gwih_f[col] + gbih_f[col]      (GRU fwd)
//   gib[v][col] = embed[v] . gwih_b[col] + gbih_b[col]      (GRU bwd)
//   gic[v][col] = embed[v] . cwih[col][64:320] + cbih[col]  (controller, embed part + bias)
// ---------------------------------------------------------------------------
__global__ __launch_bounds__(256) void k_tok_gi(
    const float* __restrict__ embed,
    const float* __restrict__ gwih_f, const float* __restrict__ gbih_f,
    const float* __restrict__ gwih_b, const float* __restrict__ gbih_b,
    const float* __restrict__ cwih,   const float* __restrict__ cbih,
    float* __restrict__ gif, float* __restrict__ gib, float* __restrict__ gic)
{
    int v = blockIdx.x, tid = threadIdx.x;
    __shared__ float es[256];
    es[tid] = embed[v * HH + tid];
    __syncthreads();
    for (int g = 0; g < 3; ++g) {
        int col = g * 256 + tid;
        float af = gbih_f[col], abv = gbih_b[col], ac = cbih[col];
        const float* wf = gwih_f + (size_t)col * HH;
        const float* wb = gwih_b + (size_t)col * HH;
        const float* wc = cwih   + (size_t)col * (HH + CONDD) + CONDD;
        for (int c = 0; c < 256; ++c) {
            float e = es[c];
            af += e * wf[c]; abv += e * wb[c]; ac += e * wc[c];
        }
        gif[v * H3 + col] = af;
        gib[v * H3 + col] = abv;
        gic[v * H3 + col] = ac;
    }
}

// ---------------------------------------------------------------------------
// w-trajectory (depends only on actions) + writes out[.,.,0..2] = A, W, w_new
// ---------------------------------------------------------------------------
__global__ void k_wtraj(const int* __restrict__ actions, const int* __restrict__ w0,
                        float* __restrict__ out, int* __restrict__ w_used)
{
    int n = threadIdx.x;  // 256 threads, 1 block
    int w = w0[n];
    for (int t = 0; t < TT; ++t) {
        int A = actions[((size_t)t * NN + n) * 2 + 0];
        int W = actions[((size_t)t * NN + n) * 2 + 1];
        w_used[t * NN + n] = w;
        int wn = w + W - NLL;
        wn = wn < 0 ? 0 : (wn > NLL - 1 ? NLL - 1 : wn);
        float* o = out + ((size_t)t * NN + n) * OW;
        o[0] = (float)A; o[1] = (float)W; o[2] = (float)wn;
        w = wn;
    }
}

// ---------------------------------------------------------------------------
// One GRU step, both directions (blockIdx.y: 0=fwd, 1=bwd).
// 16 batch rows / block. gh = H @ whhT (K=256), gates, fused B projection
// (H -> NE=8, sigmoid) so yf/yb never hit memory.
//   fwd: scan position j = step;  bwd: j = 15 - step (reverse scan).
//   input token for (i,n) at pos j: lines[n][(i+j) % 16].
// ---------------------------------------------------------------------------
__global__ __launch_bounds__(256) void k_gru_step(
    float* __restrict__ Hf, float* __restrict__ Hb,
    const float* __restrict__ whhT_f, const float* __restrict__ whhT_b,
    const float* __restrict__ gif, const float* __restrict__ gib,
    const float* __restrict__ gbhh_f, const float* __restrict__ gbhh_b,
    const float* __restrict__ w2, const float* __restrict__ b2,
    float* __restrict__ Bf, float* __restrict__ Bb,
    const int* __restrict__ lines, int step)
{
    const int dir = blockIdx.y;
    float*       H      = dir ? Hb : Hf;
    const float* whhT   = dir ? whhT_b : whhT_f;
    const float* gi_tok = dir ? gib : gif;
    const float* bhh    = dir ? gbhh_b : gbhh_f;
    float*       Bout   = dir ? Bb : Bf;
    const int j  = dir ? (15 - step) : step;
    const int r0 = blockIdx.x * 16;
    const int tid = threadIdx.x;

    // A-tile in LDS, [c][r] layout, stride 20 floats (16B-aligned for float4)
    __shared__ float As[256 * 20];

    #pragma unroll
    for (int q = 0; q < 16; ++q)
        As[tid * 20 + q] = H[(size_t)(r0 + q) * HH + tid];
    __syncthreads();

    float acc0[16], acc1[16], acc2[16];
    #pragma unroll
    for (int r = 0; r < 16; ++r) { acc0[r] = 0.f; acc1[r] = 0.f; acc2[r] = 0.f; }

    // gh GEMM: thread owns cols {tid, tid+256, tid+512} for 16 rows
    for (int c = 0; c < 256; ++c) {
        float b0v = whhT[(size_t)c * H3 + tid];
        float b1v = whhT[(size_t)c * H3 + 256 + tid];
        float b2v = whhT[(size_t)c * H3 + 512 + tid];
        const float4* a4 = (const float4*)(&As[c * 20]);
        #pragma unroll
        for (int rq = 0; rq < 4; ++rq) {
            float4 av = a4[rq];
            acc0[rq*4+0] += av.x * b0v; acc1[rq*4+0] += av.x * b1v; acc2[rq*4+0] += av.x * b2v;
            acc0[rq*4+1] += av.y * b0v; acc1[rq*4+1] += av.y * b1v; acc2[rq*4+1] += av.y * b2v;
            acc0[rq*4+2] += av.z * b0v; acc1[rq*4+2] += av.z * b1v; acc2[rq*4+2] += av.z * b2v;
            acc0[rq*4+3] += av.w * b0v; acc1[rq*4+3] += av.w * b1v; acc2[rq*4+3] += av.w * b2v;
        }
    }

    float bh0 = bhh[tid], bh1 = bhh[256 + tid], bh2 = bhh[512 + tid];
    float hnew[16];
    #pragma unroll
    for (int r = 0; r < 16; ++r) {
        int row = r0 + r;
        int i = row >> 8, n = row & 255;
        int tok = lines[n * NLL + ((i + j) & 15)];
        const float* gi = gi_tok + (size_t)tok * H3;
        float rg = sigm(gi[tid]       + acc0[r] + bh0);
        float zg = sigm(gi[256 + tid] + acc1[r] + bh1);
        float ng = tanhfast(gi[512 + tid] + rg * (acc2[r] + bh2));
        float ho = As[tid * 20 + r];
        hnew[r] = (1.f - zg) * ng + zg * ho;
    }
    __syncthreads();   // all GEMM reads of As done before overwrite
    #pragma unroll
    for (int r = 0; r < 16; ++r) {
        As[tid * 20 + r] = hnew[r];
        H[(size_t)(r0 + r) * HH + tid] = hnew[r];
    }
    __syncthreads();

    // fused B projection: B[i][n][j][e] = sigmoid(h . w2[e] + b2[e])
    if (tid < 128) {
        int r = tid >> 3, e = tid & 7;
        float a = b2[e];
        const float* w2r = w2 + e * HH;
        for (int c = 0; c < 256; ++c) a += As[c * 20 + r] * w2r[c];
        int row = r0 + r;
        int i = row >> 8, n = row & 255;
        Bout[(((size_t)i * NN + n) * NLL + j) * NEE + e] = sigm(a);
    }
}

// ---------------------------------------------------------------------------
// Stick-breaking + both reversals + roll(-1,1) into final P layout.
// One thread per (i,n,e) = 32768 threads. Writes P_final[i'][n][k'][e]:
//   Bc[2m] = Bf[i][n][m][e];  Bc[2m+1] = Bb[i][n][15-m][e]
//   P_sb[k] = (k<31 ? Bc[k] : 1) * prod_{m<k}(1-Bc[m])
//   Pcat[kk<16] = P_sb[31-2kk]; Pcat[16+m] = P_sb[2m]
//   P_final[i'][n][k'] = Pcat[(i'+1)%16][n][(k'-1)%32]
//   => thread(i) writes Pcat[kk] to P_final[(i+15)%16][n][(kk+1)%32]
//   even k=2m  -> kk=16+m -> k' = (17+m)&31
//   odd  k=2m+1-> kk=15-m -> k' = 16-m
// ---------------------------------------------------------------------------
__global__ __launch_bounds__(256) void k_stick(
    const float* __restrict__ Bf, const float* __restrict__ Bb,
    float* __restrict__ P_final)
{
    int idx = blockIdx.x * 256 + threadIdx.x;
    if (idx >= 16 * 256 * 8) return;
    int e = idx & 7, n = (idx >> 3) & 255, i = idx >> 11;
    const float* bf = Bf + ((size_t)(i * NN + n) * NLL) * NEE + e;
    const float* bb = Bb + ((size_t)(i * NN + n) * NLL) * NEE + e;
    int i2 = (i + 15) & 15;
    float* dst = P_final + ((size_t)(i2 * NN + n) * 32) * NEE + e;
    float cum = 1.f;
    #pragma unroll
    for (int m = 0; m < 16; ++m) {
        float c0 = bf[m * NEE];             // Bc[2m]   (forward)
        float c1 = bb[(15 - m) * NEE];      // Bc[2m+1] (backward, reversed)
        float v0 = c0 * cum;                // P_sb[2m]
        cum *= (1.f - c0);
        float v1 = (m < 15) ? c1 * cum : cum;  // P_sb[2m+1]; k=31 uses B2=1
        cum *= (1.f - c1);
        dst[(size_t)(((17 + m) & 31)) * NEE] = v0;
        dst[(size_t)((16 - m)) * NEE]        = v1;
    }
}

// ---------------------------------------------------------------------------
// Controller scan: persistent kernel, 2 batch rows per block (128 blocks),
// all T=32 steps inside with __syncthreads between phases.
// ---------------------------------------------------------------------------
__global__ __launch_bounds__(256) void k_ctrl(
    const float* __restrict__ condition, const int* __restrict__ lines,
    const float* __restrict__ h0, const int* __restrict__ w_used,
    const float* __restrict__ gic_tok,      // (64,768) embed part + cbih
    const float* __restrict__ cwih_condT,   // (64,768)
    const float* __restrict__ cwhhT,        // (256,768)
    const float* __restrict__ cbhh,
    const float* __restrict__ mw1T, const float* __restrict__ mb1,
    const float* __restrict__ mw2T, const float* __restrict__ mb2,
    const float* __restrict__ aw, const float* __restrict__ ab,
    const float* __restrict__ ow, const float* __restrict__ ob,
    const float* __restrict__ cw, const float* __restrict__ cb,
    const float* __restrict__ P_final,
    float* __restrict__ out)
{
    const int n0 = blockIdx.x * 2;
    const int tid = threadIdx.x;
    __shared__ float hs[2][256], gis[2][768], ghs[2][768], conds[2][64];
    __shared__ float z1s[2][256], zs[2][256], os8[2][8], heads[2][25];
    __shared__ int w_s[2], tok_s[2];

    hs[0][tid] = h0[(size_t)n0 * HH + tid];
    hs[1][tid] = h0[(size_t)(n0 + 1) * HH + tid];
    __syncthreads();

    for (int t = 0; t < TT; ++t) {
        if (tid < 128) {
            int rr = tid >> 6, cc = tid & 63;
            conds[rr][cc] = condition[((size_t)t * NN + n0 + rr) * CONDD + cc];
        }
        if (tid < 2) {
            int w = w_used[t * NN + n0 + tid];
            w_s[tid] = w;
            tok_s[tid] = lines[(n0 + tid) * NLL + w];
        }
        __syncthreads();

        // Phase A: gate pre-activations (gi: token table + cond GEMV; gh: h GEMV)
        {
            int tok0 = tok_s[0], tok1 = tok_s[1];
            const float* g0p = gic_tok + (size_t)tok0 * H3;
            const float* g1p = gic_tok + (size_t)tok1 * H3;
            float a00 = g0p[tid],       a01 = g1p[tid];
            float a10 = g0p[256 + tid], a11 = g1p[256 + tid];
            float a20 = g0p[512 + tid], a21 = g1p[512 + tid];
            for (int cc = 0; cc < 64; ++cc) {
                const float* wp = cwih_condT + (size_t)cc * H3;
                float w0v = wp[tid], w1v = wp[256 + tid], w2v = wp[512 + tid];
                float c0 = conds[0][cc], c1 = conds[1][cc];
                a00 += c0 * w0v; a01 += c1 * w0v;
                a10 += c0 * w1v; a11 += c1 * w1v;
                a20 += c0 * w2v; a21 += c1 * w2v;
            }
            gis[0][tid] = a00; gis[1][tid] = a01;
            gis[0][256 + tid] = a10; gis[1][256 + tid] = a11;
            gis[0][512 + tid] = a20; gis[1][512 + tid] = a21;

            float g00 = cbhh[tid],      g01 = g00;
            float g10 = cbhh[256 + tid], g11 = g10;
            float g20 = cbhh[512 + tid], g21 = g20;
            for (int c = 0; c < 256; ++c) {
                const float* wp = cwhhT + (size_t)c * H3;
                float w0v = wp[tid], w1v = wp[256 + tid], w2v = wp[512 + tid];
                float h0v = hs[0][c], h1v = hs[1][c];
                g00 += h0v * w0v; g01 += h1v * w0v;
                g10 += h0v * w1v; g11 += h1v * w1v;
                g20 += h0v * w2v; g21 += h1v * w2v;
            }
            ghs[0][tid] = g00; ghs[1][tid] = g01;
            ghs[0][256 + tid] = g10; ghs[1][256 + tid] = g11;
            ghs[0][512 + tid] = g20; ghs[1][512 + tid] = g21;
        }
        __syncthreads();

        // Gate update (each thread: its column, both rows)
        #pragma unroll
        for (int rr = 0; rr < 2; ++rr) {
            float rg = sigm(gis[rr][tid] + ghs[rr][tid]);
            float zg = sigm(gis[rr][256 + tid] + ghs[rr][256 + tid]);
            float ng = tanhfast(gis[rr][512 + tid] + rg * ghs[rr][512 + tid]);
            float hn = (1.f - zg) * ng + zg * hs[rr][tid];
            hs[rr][tid] = hn;
            out[((size_t)t * NN + n0 + rr) * OW + 4 + tid] = hn;
        }
        __syncthreads();

        // MLP layer 1
        {
            float a0 = mb1[tid], a1 = a0;
            for (int c = 0; c < 256; ++c) {
                float wv = mw1T[(size_t)c * 256 + tid];
                a0 += hs[0][c] * wv; a1 += hs[1][c] * wv;
            }
            z1s[0][tid] = fmaxf(a0, 0.f); z1s[1][tid] = fmaxf(a1, 0.f);
        }
        __syncthreads();
        // MLP layer 2 (relu(relu(.)) == relu(.))
        {
            float a0 = mb2[tid], a1 = a0;
            for (int c = 0; c < 256; ++c) {
                float wv = mw2T[(size_t)c * 256 + tid];
                a0 += z1s[0][c] * wv; a1 += z1s[1][c] * wv;
            }
            zs[0][tid] = fmaxf(a0, 0.f); zs[1][tid] = fmaxf(a1, 0.f);
        }
        __syncthreads();

        // Heads: 25 dots per row (16 a-logits, 8 o-logits, 1 v)
        if (tid < 50) {
            int rr = tid / 25, which = tid % 25;
            const float* wrow; float bias;
            if (which < 16)      { wrow = aw + which * HH;        bias = ab[which]; }
            else if (which < 24) { wrow = ow + (which - 16) * HH; bias = ob[which - 16]; }
            else                 { wrow = cw;                     bias = cb[0]; }
            float a = bias;
            for (int c = 0; c < 256; ++c) a += zs[rr][c] * wrow[c];
            heads[rr][which] = a;
        }
        __syncthreads();

        // Softmaxes + v
        if (tid < 4) {
            int rr = tid >> 1, kind = tid & 1;
            float* orow = out + ((size_t)t * NN + n0 + rr) * OW;
            if (kind == 0) {
                float mx = heads[rr][0];
                for (int k = 1; k < 16; ++k) mx = fmaxf(mx, heads[rr][k]);
                float s = 0.f;
                for (int k = 0; k < 16; ++k) s += __expf(heads[rr][k] - mx);
                float inv = 1.f / s;
                for (int k = 0; k < 16; ++k) orow[260 + k] = __expf(heads[rr][k] - mx) * inv;
                orow[3] = heads[rr][24];   // v
            } else {
                float mx = heads[rr][16];
                for (int k = 1; k < 8; ++k) mx = fmaxf(mx, heads[rr][16 + k]);
                float s = 0.f;
                for (int k = 0; k < 8; ++k) s += __expf(heads[rr][16 + k] - mx);
                float inv = 1.f / s;
                for (int k = 0; k < 8; ++k) os8[rr][k] = __expf(heads[rr][16 + k] - mx) * inv;
            }
        }
        __syncthreads();

        // p_probs[n][k] = sum_e P_final[w][n][k][e] * o[e]
        if (tid < 64) {
            int rr = tid >> 5, k = tid & 31;
            const float* g = P_final + (((size_t)w_s[rr] * NN + (n0 + rr)) * 32 + k) * NEE;
            float a = 0.f;
            #pragma unroll
            for (int e = 0; e < 8; ++e) a += g[e] * os8[rr][e];
            out[((size_t)t * NN + n0 + rr) * OW + 276 + k] = a;
        }
        __syncthreads();   // protect w_s/conds/os8 for next iteration
    }
}

// ---------------------------------------------------------------------------
extern "C" void kernel_launch(void* const* d_in, const int* in_sizes, int n_in,
                              void* d_out, int out_size, void* d_ws, size_t ws_size,
                              hipStream_t stream) {
    const float* condition = (const float*)d_in[0];
    const int*   lines     = (const int*)  d_in[1];
    const int*   actions   = (const int*)  d_in[2];
    const float* h0        = (const float*)d_in[3];
    const int*   w0        = (const int*)  d_in[4];
    const float* embed     = (const float*)d_in[5];
    const float* gwih_f    = (const float*)d_in[6];
    const float* gwhh_f    = (const float*)d_in[7];
    const float* gbih_f    = (const float*)d_in[8];
    const float* gbhh_f    = (const float*)d_in[9];
    const float* gwih_b    = (const float*)d_in[10];
    const float* gwhh_b    = (const float*)d_in[11];
    const float* gbih_b    = (const float*)d_in[12];
    const float* gbhh_b    = (const float*)d_in[13];
    const float* w2        = (const float*)d_in[14];
    const float* b2        = (const float*)d_in[15];
    const float* cwih      = (const float*)d_in[16];
    const float* cwhh      = (const float*)d_in[17];
    const float* cbih      = (const float*)d_in[18];
    const float* cbhh      = (const float*)d_in[19];
    const float* mw1       = (const float*)d_in[20];
    const float* mb1       = (const float*)d_in[21];
    const float* mw2       = (const float*)d_in[22];
    const float* mb2       = (const float*)d_in[23];
    const float* ow        = (const float*)d_in[24];
    const float* ob        = (const float*)d_in[25];
    const float* aw        = (const float*)d_in[26];
    const float* ab        = (const float*)d_in[27];
    const float* cw        = (const float*)d_in[28];
    const float* cb        = (const float*)d_in[29];
    float* out = (float*)d_out;

    // Workspace carve-up (~20.5 MB of f32 + 32 KB int)
    float* p = (float*)d_ws;
    float* whhT_f     = p; p += 256 * H3;
    float* whhT_b     = p; p += 256 * H3;
    float* cwhhT      = p; p += 256 * H3;
    float* mw1T       = p; p += 256 * 256;
    float* mw2T       = p; p += 256 * 256;
    float* cwih_condT = p; p += 64 * H3;
    float* gif_tok    = p; p += 64 * H3;
    float* gib_tok    = p; p += 64 * H3;
    float* gic_tok    = p; p += 64 * H3;
    float* Hf         = p; p += 4096 * 256;
    float* Hb         = p; p += 4096 * 256;   // contiguous with Hf (one memset)
    float* Bf         = p; p += 16 * 256 * 16 * 8;
    float* Bb         = p; p += 16 * 256 * 16 * 8;
    float* P_final    = p; p += 16 * 256 * 32 * 8;
    int*   w_used     = (int*)p;

    // Weight transposes (coalesced-read GEMV layouts)
    k_transpose_sub<<<(768 * 256 + 255) / 256, 256, 0, stream>>>(gwhh_f, whhT_f, 768, 256, 0, 256);
    k_transpose_sub<<<(768 * 256 + 255) / 256, 256, 0, stream>>>(gwhh_b, whhT_b, 768, 256, 0, 256);
    k_transpose_sub<<<(768 * 256 + 255) / 256, 256, 0, stream>>>(cwhh,   cwhhT,  768, 256, 0, 256);
    k_transpose_sub<<<(256 * 256 + 255) / 256, 256, 0, stream>>>(mw1,    mw1T,   256, 256, 0, 256);
    k_transpose_sub<<<(256 * 256 + 255) / 256, 256, 0, stream>>>(mw2,    mw2T,   256, 256, 0, 256);
    k_transpose_sub<<<(768 * 64  + 255) / 256, 256, 0, stream>>>(cwih, cwih_condT, 768, 320, 0, 64);

    // Per-token input projections (64 tokens)
    k_tok_gi<<<64, 256, 0, stream>>>(embed, gwih_f, gbih_f, gwih_b, gbih_b, cwih, cbih,
                                     gif_tok, gib_tok, gic_tok);

    // w trajectory + out[...,0..2]
    k_wtraj<<<1, 256, 0, stream>>>(actions, w0, out, w_used);

    // GRU states start at zero
    hipMemsetAsync(Hf, 0, (size_t)4096 * 256 * 2 * sizeof(float), stream);

    // Bidirectional GRU scan, 16 sequential steps, fwd+bwd per launch
    for (int s = 0; s < 16; ++s)
        k_gru_step<<<dim3(256, 2), 256, 0, stream>>>(Hf, Hb, whhT_f, whhT_b,
                                                     gif_tok, gib_tok, gbhh_f, gbhh_b,
                                                     w2, b2, Bf, Bb, lines, s);

    // Stick-breaking -> P_final (roll applied)
    k_stick<<<128, 256, 0, stream>>>(Bf, Bb, P_final);

    // Controller scan (persistent; writes out[...,3..307])
    k_ctrl<<<128, 256, 0, stream>>>(condition, lines, h0, w_used,
                                    gic_tok, cwih_condT, cwhhT, cbhh,
                                    mw1T, mb1, mw2T, mb2,
                                    aw, ab, ow, ob, cw, cb,
                                    P_final, out);
}

// Round 2
// 1330.725 us; speedup vs baseline: 1.3042x; 1.3042x over previous
//
#include <hip/hip_runtime.h>
#include <cstddef>

#define TT   32
#define NN   256
#define NLL  16
#define HH   256
#define CONDD 64
#define NEE  8
#define H3   768
#define OW   308

typedef __attribute__((ext_vector_type(8))) short bf16x8;
typedef __attribute__((ext_vector_type(4))) float f32x4;
typedef unsigned short u16;

__device__ __forceinline__ float sigm(float x)     { return 1.f / (1.f + __expf(-x)); }
__device__ __forceinline__ float tanhfast(float x) { return 1.f - 2.f / (__expf(2.f * x) + 1.f); }
__device__ __forceinline__ float bf2f(u16 h) {
    union { unsigned u; float f; } v; v.u = ((unsigned)h) << 16; return v.f;
}
__device__ __forceinline__ u16 f2bf(float f) {   // round-to-nearest-even
    union { float f; unsigned u; } v; v.f = f;
    unsigned r = v.u + 0x7fffu + ((v.u >> 16) & 1u);
    return (u16)(r >> 16);
}
#define MFMA(a, b, c) __builtin_amdgcn_mfma_f32_16x16x32_bf16(a, b, c, 0, 0, 0)

// ---------------------------------------------------------------------------
// fp32 -> bf16 casts
// ---------------------------------------------------------------------------
__global__ void k_cast(const float* __restrict__ s, u16* __restrict__ d, int n) {
    int i = blockIdx.x * 256 + threadIdx.x;
    if (i < n) d[i] = f2bf(s[i]);
}
// cwih (768,320) -> cond part (768,64) bf16
__global__ void k_cast_cwc(const float* __restrict__ cwih, u16* __restrict__ d) {
    int i = blockIdx.x * 256 + threadIdx.x;
    if (i < 768 * 64) { int r = i >> 6, c = i & 63; d[i] = f2bf(cwih[r * 320 + c]); }
}

// ---------------------------------------------------------------------------
// Per-token input projections (bf16 tables, biases folded in)
// ---------------------------------------------------------------------------
__global__ __launch_bounds__(256) void k_tok_gi(
    const float* __restrict__ embed,
    const float* __restrict__ gwih_f, const float* __restrict__ gbih_f,
    const float* __restrict__ gwih_b, const float* __restrict__ gbih_b,
    const float* __restrict__ cwih,   const float* __restrict__ cbih,
    u16* __restrict__ gif, u16* __restrict__ gib, u16* __restrict__ gic)
{
    int v = blockIdx.x, tid = threadIdx.x;
    __shared__ float es[256];
    es[tid] = embed[v * HH + tid];
    __syncthreads();
    for (int g = 0; g < 3; ++g) {
        int col = g * 256 + tid;
        float af = gbih_f[col], abv = gbih_b[col], ac = cbih[col];
        const float* wf = gwih_f + (size_t)col * HH;
        const float* wb = gwih_b + (size_t)col * HH;
        const float* wc = cwih   + (size_t)col * (HH + CONDD) + CONDD;
        for (int c = 0; c < 256; ++c) {
            float e = es[c];
            af += e * wf[c]; abv += e * wb[c]; ac += e * wc[c];
        }
        gif[v * H3 + col] = f2bf(af);
        gib[v * H3 + col] = f2bf(abv);
        gic[v * H3 + col] = f2bf(ac);
    }
}

// ---------------------------------------------------------------------------
// w-trajectory + out[.,.,0..2]
// ---------------------------------------------------------------------------
__global__ void k_wtraj(const int* __restrict__ actions, const int* __restrict__ w0,
                        float* __restrict__ out, int* __restrict__ w_used)
{
    int n = threadIdx.x;
    int w = w0[n];
    for (int t = 0; t < TT; ++t) {
        int A = actions[((size_t)t * NN + n) * 2 + 0];
        int W = actions[((size_t)t * NN + n) * 2 + 1];
        w_used[t * NN + n] = w;
        int wn = w + W - NLL;
        wn = wn < 0 ? 0 : (wn > NLL - 1 ? NLL - 1 : wn);
        float* o = out + ((size_t)t * NN + n) * OW;
        o[0] = (float)A; o[1] = (float)W; o[2] = (float)wn;
        w = wn;
    }
}

// ---------------------------------------------------------------------------
// MEGA persistent kernel.
//   bid < 256 : GRU role. 32 rows/block (block entirely fwd or bwd). 16 steps.
//               h kept in LDS (bf16 for MFMA A-frags, fp32 tile for B-proj).
//   bid >= 256: controller role (16 blocks x 16 batch rows). 32 steps.
//               gh = h@cwhh^T (K=256) + cond@cwihc^T (K=64) fused in MFMA acc;
//               n-gate cond part kept in separate acc (r-gating only scales gh).
// MFMA frag convention (k-permutation consistent across A and B):
//   A: m=lane&15, k elems = ks*32 + (lane>>4)*8 + e  (16B contiguous load)
//   B: n=lane&15, same k elems; B[k][n] = Wrowmajor[n][k] -> 16B contiguous
//   C: col=lane&15, row=(lane>>4)*4+reg   (m89-verified)
// ---------------------------------------------------------------------------
__global__ __launch_bounds__(512) void k_mega(
    const u16* __restrict__ whhbf_f, const u16* __restrict__ whhbf_b,
    const u16* __restrict__ gif, const u16* __restrict__ gib,
    const float* __restrict__ gbhh_f, const float* __restrict__ gbhh_b,
    const float* __restrict__ w2, const float* __restrict__ b2,
    float* __restrict__ Bf, float* __restrict__ Bb,
    const int* __restrict__ lines,
    const u16* __restrict__ cwhhbf, const u16* __restrict__ cwcbf,
    const u16* __restrict__ condbf, const u16* __restrict__ gic,
    const float* __restrict__ cbhh, const float* __restrict__ h0,
    const int* __restrict__ w_used,
    u16* __restrict__ Hallbf, float* __restrict__ out)
{
    __shared__ __align__(16) char smem[51968];
    const int bid  = blockIdx.x;
    const int tid  = threadIdx.x;
    const int lane = tid & 63;
    const int lm   = lane & 15, lg = lane >> 4;

    if (bid < 256) {
        // ---------------- GRU role ----------------
        u16*   hbf  = (u16*)smem;                       // [32][264] bf16
        float* hf32 = (float*)(smem + 16896);           // [32][258] f32
        int*   lns  = (int*)(smem + 16896 + 33024);     // [32][16]
        const int dir = bid >> 7;
        const int lb  = bid & 127;
        const int ii  = lb >> 3;
        const int nb  = (lb & 7) * 32;
        const u16*   whh  = dir ? whhbf_b : whhbf_f;
        const u16*   git  = dir ? gib : gif;
        const float* bhh  = dir ? gbhh_b : gbhh_f;
        float*       Bout = dir ? Bb : Bf;
        const int w = tid >> 6;   // wave 0..7, owns cols w*32..w*32+31 per chunk

        for (int k = tid; k < 32 * 264; k += 512) hbf[k] = 0;
        { int r = tid >> 4, c = tid & 15; lns[r * 16 + c] = lines[(nb + r) * 16 + c]; }
        __syncthreads();

        for (int s = 0; s < 16; ++s) {
            const int jpos = dir ? (15 - s) : s;
            f32x4 acc[3][2][2];
            #pragma unroll
            for (int q = 0; q < 3; ++q)
                #pragma unroll
                for (int c = 0; c < 2; ++c)
                    #pragma unroll
                    for (int r = 0; r < 2; ++r)
                        #pragma unroll
                        for (int z = 0; z < 4; ++z) acc[q][c][r][z] = 0.f;

            #pragma unroll
            for (int ks = 0; ks < 8; ++ks) {
                bf16x8 a0 = *(const bf16x8*)&hbf[lm * 264 + ks * 32 + lg * 8];
                bf16x8 a1 = *(const bf16x8*)&hbf[(16 + lm) * 264 + ks * 32 + lg * 8];
                #pragma unroll
                for (int q = 0; q < 3; ++q)
                    #pragma unroll
                    for (int cf = 0; cf < 2; ++cf) {
                        const u16* bp = whh + (size_t)(q * 256 + w * 32 + cf * 16 + lm) * 256
                                        + ks * 32 + lg * 8;
                        bf16x8 b = *(const bf16x8*)bp;
                        acc[q][cf][0] = MFMA(a0, b, acc[q][cf][0]);
                        acc[q][cf][1] = MFMA(a1, b, acc[q][cf][1]);
                    }
            }
            // gates -> hf32 tile
            #pragma unroll
            for (int cf = 0; cf < 2; ++cf) {
                int col = w * 32 + cf * 16 + lm;
                float br = bhh[col], bz = bhh[col + 256], bn = bhh[col + 512];
                #pragma unroll
                for (int rf = 0; rf < 2; ++rf)
                    #pragma unroll
                    for (int j = 0; j < 4; ++j) {
                        int lrow = rf * 16 + lg * 4 + j;
                        int tok  = lns[lrow * 16 + ((ii + jpos) & 15)];
                        const u16* gi = git + (size_t)tok * H3;
                        float ho = bf2f(hbf[lrow * 264 + col]);
                        float rg = sigm(bf2f(gi[col])       + acc[0][cf][rf][j] + br);
                        float zg = sigm(bf2f(gi[col + 256]) + acc[1][cf][rf][j] + bz);
                        float ng = tanhfast(bf2f(gi[col + 512]) + rg * (acc[2][cf][rf][j] + bn));
                        hf32[lrow * 258 + col] = (1.f - zg) * ng + zg * ho;
                    }
            }
            __syncthreads();
            // hbf <- bf16(hf32)
            {
                int lrow = tid >> 4, c0 = (tid & 15) * 16;
                u16 tmp[16];
                #pragma unroll
                for (int k = 0; k < 16; ++k) tmp[k] = f2bf(hf32[lrow * 258 + c0 + k]);
                *(uint4*)&hbf[lrow * 264 + c0]     = *(uint4*)&tmp[0];
                *(uint4*)&hbf[lrow * 264 + c0 + 8] = *(uint4*)&tmp[8];
            }
            // fused B projection (fp32 h)
            if (tid < 256) {
                int r = tid >> 3, e = tid & 7;
                float a = b2[e];
                const float* w2r = w2 + e * 256;
                for (int c = 0; c < 256; ++c) a += hf32[r * 258 + c] * w2r[c];
                int grow = ii * 256 + nb + r;
                Bout[((size_t)grow * NLL + jpos) * NEE + e] = sigm(a);
            }
            __syncthreads();
        }
    } else {
        // ---------------- controller role ----------------
        u16* hc = (u16*)smem;            // [16][264] bf16
        const int cb = bid - 256;        // 0..15, rows cb*16..cb*16+15
        if (tid < 256) {
            int lrow = tid >> 4, c0 = (tid & 15) * 16;
            u16 tmp[16];
            #pragma unroll
            for (int k = 0; k < 16; ++k)
                tmp[k] = f2bf(h0[(size_t)(cb * 16 + lrow) * 256 + c0 + k]);
            *(uint4*)&hc[lrow * 264 + c0]     = *(uint4*)&tmp[0];
            *(uint4*)&hc[lrow * 264 + c0 + 8] = *(uint4*)&tmp[8];
        }
        __syncthreads();
        const int w = tid >> 6;  // 0..3 for active threads

        for (int t = 0; t < TT; ++t) {
            f32x4 accM[3][4], accC[4];
            if (tid < 256) {
                #pragma unroll
                for (int q = 0; q < 3; ++q)
                    #pragma unroll
                    for (int c = 0; c < 4; ++c)
                        #pragma unroll
                        for (int z = 0; z < 4; ++z) accM[q][c][z] = 0.f;
                #pragma unroll
                for (int c = 0; c < 4; ++c)
                    #pragma unroll
                    for (int z = 0; z < 4; ++z) accC[c][z] = 0.f;

                // h @ cwhh^T  (K=256)
                #pragma unroll
                for (int ks = 0; ks < 8; ++ks) {
                    bf16x8 a = *(const bf16x8*)&hc[lm * 264 + ks * 32 + lg * 8];
                    #pragma unroll
                    for (int q = 0; q < 3; ++q)
                        #pragma unroll
                        for (int cf = 0; cf < 4; ++cf) {
                            const u16* bp = cwhhbf + (size_t)(q * 256 + w * 64 + cf * 16 + lm) * 256
                                            + ks * 32 + lg * 8;
                            accM[q][cf] = MFMA(a, *(const bf16x8*)bp, accM[q][cf]);
                        }
                }
                // cond @ cwih_cond^T  (K=64); chunks r,z merge; n-chunk separate
                #pragma unroll
                for (int ks = 0; ks < 2; ++ks) {
                    bf16x8 a = *(const bf16x8*)&condbf[(size_t)(t * 256 + cb * 16 + lm) * 64
                                                       + ks * 32 + lg * 8];
                    #pragma unroll
                    for (int q = 0; q < 3; ++q)
                        #pragma unroll
                        for (int cf = 0; cf < 4; ++cf) {
                            const u16* bp = cwcbf + (size_t)(q * 256 + w * 64 + cf * 16 + lm) * 64
                                            + ks * 32 + lg * 8;
                            bf16x8 b = *(const bf16x8*)bp;
                            if (q < 2) accM[q][cf] = MFMA(a, b, accM[q][cf]);
                            else       accC[cf]    = MFMA(a, b, accC[cf]);
                        }
                }
            }
            __syncthreads();   // all hc reads complete
            if (tid < 256) {
                #pragma unroll
                for (int cf = 0; cf < 4; ++cf) {
                    int col = w * 64 + cf * 16 + lm;
                    float br = cbhh[col], bz = cbhh[col + 256], bn = cbhh[col + 512];
                    #pragma unroll
                    for (int j = 0; j < 4; ++j) {
                        int lrow = lg * 4 + j;
                        int n = cb * 16 + lrow;
                        int wv = w_used[t * 256 + n];
                        int tok = lines[n * 16 + wv];
                        const u16* gi = gic + (size_t)tok * H3;
                        float ho = bf2f(hc[lrow * 264 + col]);
                        float rg = sigm(bf2f(gi[col])       + accM[0][cf][j] + br);
                        float zg = sigm(bf2f(gi[col + 256]) + accM[1][cf][j] + bz);
                        float ng = tanhfast(bf2f(gi[col + 512]) + accC[cf][j]
                                            + rg * (accM[2][cf][j] + bn));
                        float hn = (1.f - zg) * ng + zg * ho;
                        out[((size_t)t * 256 + n) * OW + 4 + col] = hn;
                        Hallbf[((size_t)t * 256 + n) * 256 + col] = f2bf(hn);
                        hc[lrow * 264 + col] = f2bf(hn);   // same-element RAW: own read done
                    }
                }
            }
            __syncthreads();   // hc ready for next step
        }
    }
}

// ---------------------------------------------------------------------------
// Stick-breaking + reversals + roll into final P layout (unchanged, verified)
// ---------------------------------------------------------------------------
__global__ __launch_bounds__(256) void k_stick(
    const float* __restrict__ Bf, const float* __restrict__ Bb,
    float* __restrict__ P_final)
{
    int idx = blockIdx.x * 256 + threadIdx.x;
    if (idx >= 16 * 256 * 8) return;
    int e = idx & 7, n = (idx >> 3) & 255, i = idx >> 11;
    const float* bf = Bf + ((size_t)(i * NN + n) * NLL) * NEE + e;
    const float* bb = Bb + ((size_t)(i * NN + n) * NLL) * NEE + e;
    int i2 = (i + 15) & 15;
    float* dst = P_final + ((size_t)(i2 * NN + n) * 32) * NEE + e;
    float cum = 1.f;
    #pragma unroll
    for (int m = 0; m < 16; ++m) {
        float c0 = bf[m * NEE];
        float c1 = bb[(15 - m) * NEE];
        float v0 = c0 * cum;
        cum *= (1.f - c0);
        float v1 = (m < 15) ? c1 * cum : cum;
        cum *= (1.f - c1);
        dst[(size_t)(((17 + m) & 31)) * NEE] = v0;
        dst[(size_t)((16 - m)) * NEE]        = v1;
    }
}

// ---------------------------------------------------------------------------
// Batched MLP layer: Out = bf16(relu(A @ W^T + bias)), A (8192,256) bf16
// ---------------------------------------------------------------------------
__global__ __launch_bounds__(256) void k_mlp(
    const u16* __restrict__ A, const u16* __restrict__ W,
    const float* __restrict__ bias, u16* __restrict__ Out)
{
    __shared__ u16 ot[32 * 264];
    const int g0 = blockIdx.x * 32;
    const int tid = threadIdx.x, lane = tid & 63, w = tid >> 6;
    const int lm = lane & 15, lg = lane >> 4;
    f32x4 acc[4][2];
    #pragma unroll
    for (int c = 0; c < 4; ++c)
        #pragma unroll
        for (int r = 0; r < 2; ++r)
            #pragma unroll
            for (int z = 0; z < 4; ++z) acc[c][r][z] = 0.f;
    #pragma unroll
    for (int ks = 0; ks < 8; ++ks) {
        bf16x8 a0 = *(const bf16x8*)&A[(size_t)(g0 + lm) * 256 + ks * 32 + lg * 8];
        bf16x8 a1 = *(const bf16x8*)&A[(size_t)(g0 + 16 + lm) * 256 + ks * 32 + lg * 8];
        #pragma unroll
        for (int cf = 0; cf < 4; ++cf) {
            const u16* bp = W + (size_t)(w * 64 + cf * 16 + lm) * 256 + ks * 32 + lg * 8;
            bf16x8 b = *(const bf16x8*)bp;
            acc[cf][0] = MFMA(a0, b, acc[cf][0]);
            acc[cf][1] = MFMA(a1, b, acc[cf][1]);
        }
    }
    #pragma unroll
    for (int cf = 0; cf < 4; ++cf) {
        int col = w * 64 + cf * 16 + lm;
        float bs = bias[col];
        #pragma unroll
        for (int rf = 0; rf < 2; ++rf)
            #pragma unroll
            for (int j = 0; j < 4; ++j) {
                int lrow = rf * 16 + lg * 4 + j;
                ot[lrow * 264 + col] = f2bf(fmaxf(acc[cf][rf][j] + bs, 0.f));
            }
    }
    __syncthreads();
    int lrow = tid >> 3, c0 = (tid & 7) * 32;
    const uint4* src = (const uint4*)&ot[lrow * 264 + c0];
    uint4* dst = (uint4*)&Out[(size_t)(g0 + lrow) * 256 + c0];
    dst[0] = src[0]; dst[1] = src[1]; dst[2] = src[2]; dst[3] = src[3];
}

// ---------------------------------------------------------------------------
// Heads: 25 logits per row + softmaxes + v + p_probs, writes out cols 3,260..307
// ---------------------------------------------------------------------------
__global__ __launch_bounds__(256) void k_heads(
    const u16* __restrict__ zbf,
    const float* __restrict__ aw, const float* __restrict__ ab,
    const float* __restrict__ ow, const float* __restrict__ ob,
    const float* __restrict__ cw, const float* __restrict__ cb,
    const float* __restrict__ P_final, const int* __restrict__ w_used,
    float* __restrict__ out)
{
    __shared__ float zt[32 * 258];
    __shared__ float hd[32][28];
    __shared__ float o8[32][8];
    __shared__ int   wv[32];
    const int g0 = blockIdx.x * 32, tid = threadIdx.x;
    {
        int lrow = tid >> 3, c0 = (tid & 7) * 32;
        const u16* src = &zbf[(size_t)(g0 + lrow) * 256 + c0];
        #pragma unroll
        for (int k = 0; k < 32; ++k) zt[lrow * 258 + c0 + k] = bf2f(src[k]);
    }
    if (tid < 32) wv[tid] = w_used[g0 + tid];
    __syncthreads();
    {
        int r = tid >> 3, s = tid & 7;
        const float* z = &zt[r * 258];
        float a1 = ab[s], a2 = ab[8 + s], a3 = ob[s], a4 = cb[0];
        const float* w1 = aw + s * 256;
        const float* w2_ = aw + (8 + s) * 256;
        const float* w3 = ow + s * 256;
        for (int c = 0; c < 256; ++c) {
            float zv = z[c];
            a1 += zv * w1[c]; a2 += zv * w2_[c]; a3 += zv * w3[c]; a4 += zv * cw[c];
        }
        hd[r][s] = a1; hd[r][8 + s] = a2; hd[r][16 + s] = a3;
        if (s == 0) hd[r][24] = a4;
    }
    __syncthreads();
    if (tid < 32) {
        int r = tid; int g = g0 + r;
        float* orow = out + (size_t)g * OW;
        float mx = hd[r][0];
        #pragma unroll
        for (int k = 1; k < 16; ++k) mx = fmaxf(mx, hd[r][k]);
        float ex[16], ssum = 0.f;
        #pragma unroll
        for (int k = 0; k < 16; ++k) { ex[k] = __expf(hd[r][k] - mx); ssum += ex[k]; }
        float inv = 1.f / ssum;
        #pragma unroll
        for (int k = 0; k < 16; ++k) orow[260 + k] = ex[k] * inv;
        orow[3] = hd[r][24];
        float mo = hd[r][16];
        #pragma unroll
        for (int k = 1; k < 8; ++k) mo = fmaxf(mo, hd[r][16 + k]);
        float eo[8], so = 0.f;
        #pragma unroll
        for (int k = 0; k < 8; ++k) { eo[k] = __expf(hd[r][16 + k] - mo); so += eo[k]; }
        float invo = 1.f / so;
        #pragma unroll
        for (int k = 0; k < 8; ++k) o8[r][k] = eo[k] * invo;
    }
    __syncthreads();
    {
        int r = tid >> 3, kb = tid & 7;
        int g = g0 + r, n = g & 255;
        const float* base = P_final + ((size_t)(wv[r] * NN + n) * 32) * NEE;
        float* orow = out + (size_t)g * OW + 276;
        #pragma unroll
        for (int m = 0; m < 4; ++m) {
            int k = kb + m * 8;
            const float* pe = base + k * NEE;
            float a = 0.f;
            #pragma unroll
            for (int e = 0; e < 8; ++e) a += pe[e] * o8[r][e];
            orow[k] = a;
        }
    }
}

// ---------------------------------------------------------------------------
extern "C" void kernel_launch(void* const* d_in, const int* in_sizes, int n_in,
                              void* d_out, int out_size, void* d_ws, size_t ws_size,
                              hipStream_t stream) {
    const float* condition = (const float*)d_in[0];
    const int*   lines     = (const int*)  d_in[1];
    const int*   actions   = (const int*)  d_in[2];
    const float* h0        = (const float*)d_in[3];
    const int*   w0        = (const int*)  d_in[4];
    const float* embed     = (const float*)d_in[5];
    const float* gwih_f    = (const float*)d_in[6];
    const float* gwhh_f    = (const float*)d_in[7];
    const float* gbih_f    = (const float*)d_in[8];
    const float* gbhh_f    = (const float*)d_in[9];
    const float* gwih_b    = (const float*)d_in[10];
    const float* gwhh_b    = (const float*)d_in[11];
    const float* gbih_b    = (const float*)d_in[12];
    const float* gbhh_b    = (const float*)d_in[13];
    const float* w2        = (const float*)d_in[14];
    const float* b2        = (const float*)d_in[15];
    const float* cwih      = (const float*)d_in[16];
    const float* cwhh      = (const float*)d_in[17];
    const float* cbih      = (const float*)d_in[18];
    const float* cbhh      = (const float*)d_in[19];
    const float* mw1       = (const float*)d_in[20];
    const float* mb1       = (const float*)d_in[21];
    const float* mw2       = (const float*)d_in[22];
    const float* mb2       = (const float*)d_in[23];
    const float* ow        = (const float*)d_in[24];
    const float* ob        = (const float*)d_in[25];
    const float* aw        = (const float*)d_in[26];
    const float* ab        = (const float*)d_in[27];
    const float* cw        = (const float*)d_in[28];
    const float* cb        = (const float*)d_in[29];
    float* out = (float*)d_out;

    // workspace carve-up (~19.3 MB peak, aliased)
    char* base = (char*)d_ws;
    auto alloc = [&](size_t bytes) { char* r = base; base += (bytes + 255) & ~(size_t)255; return r; };
    u16*   gif_tok = (u16*)alloc(64 * H3 * 2);
    u16*   gib_tok = (u16*)alloc(64 * H3 * 2);
    u16*   gic_tok = (u16*)alloc(64 * H3 * 2);
    u16*   whhbf_f = (u16*)alloc(H3 * 256 * 2);
    u16*   whhbf_b = (u16*)alloc(H3 * 256 * 2);
    u16*   cwhhbf  = (u16*)alloc(H3 * 256 * 2);
    u16*   mw1bf   = (u16*)alloc(256 * 256 * 2);
    u16*   mw2bf   = (u16*)alloc(256 * 256 * 2);
    u16*   cwcbf   = (u16*)alloc(H3 * 64 * 2);
    u16*   condbf  = (u16*)alloc((size_t)TT * NN * CONDD * 2);
    float* Bf      = (float*)alloc((size_t)16 * 256 * 16 * 8 * 4);   // aliased: z1bf
    float* Bb      = (float*)alloc((size_t)16 * 256 * 16 * 8 * 4);   // (contiguous w/ Bf)
    float* P_final = (float*)alloc((size_t)16 * 256 * 32 * 8 * 4);
    u16*   Hallbf  = (u16*)alloc((size_t)TT * NN * 256 * 2);
    u16*   zbf     = (u16*)alloc((size_t)TT * NN * 256 * 2);
    int*   w_used  = (int*)alloc((size_t)TT * NN * 4);
    u16*   z1bf    = (u16*)Bf;   // reuse Bf+Bb (4 MB) after k_stick

    // bf16 weight/activation conversions
    k_cast<<<(196608 + 255) / 256, 256, 0, stream>>>(gwhh_f, whhbf_f, 196608);
    k_cast<<<(196608 + 255) / 256, 256, 0, stream>>>(gwhh_b, whhbf_b, 196608);
    k_cast<<<(196608 + 255) / 256, 256, 0, stream>>>(cwhh, cwhhbf, 196608);
    k_cast<<<(65536 + 255) / 256, 256, 0, stream>>>(mw1, mw1bf, 65536);
    k_cast<<<(65536 + 255) / 256, 256, 0, stream>>>(mw2, mw2bf, 65536);
    k_cast<<<(524288 + 255) / 256, 256, 0, stream>>>(condition, condbf, 524288);
    k_cast_cwc<<<192, 256, 0, stream>>>(cwih, cwcbf);

    k_tok_gi<<<64, 256, 0, stream>>>(embed, gwih_f, gbih_f, gwih_b, gbih_b, cwih, cbih,
                                     gif_tok, gib_tok, gic_tok);
    k_wtraj<<<1, 256, 0, stream>>>(actions, w0, out, w_used);

    // GRU (256 blocks) + controller (16 blocks), persistent, concurrent
    k_mega<<<272, 512, 0, stream>>>(whhbf_f, whhbf_b, gif_tok, gib_tok, gbhh_f, gbhh_b,
                                    w2, b2, Bf, Bb, lines,
                                    cwhhbf, cwcbf, condbf, gic_tok, cbhh, h0, w_used,
                                    Hallbf, out);

    k_stick<<<128, 256, 0, stream>>>(Bf, Bb, P_final);

    k_mlp<<<256, 256, 0, stream>>>(Hallbf, mw1bf, mb1, z1bf);
    k_mlp<<<256, 256, 0, stream>>>(z1bf, mw2bf, mb2, zbf);

    k_heads<<<256, 256, 0, stream>>>(zbf, aw, ab, ow, ob, cw, cb, P_final, w_used, out);
}

// Round 3
// 1323.122 us; speedup vs baseline: 1.3117x; 1.0057x over previous
//
#include <hip/hip_runtime.h>
#include <cstddef>

#define TT   32
#define NN   256
#define NLL  16
#define HH   256
#define CONDD 64
#define NEE  8
#define H3   768
#define OW   308

typedef __attribute__((ext_vector_type(8))) short bf16x8;
typedef __attribute__((ext_vector_type(4))) float f32x4;
typedef unsigned short u16;

__device__ __forceinline__ float sigm(float x)     { return 1.f / (1.f + __expf(-x)); }
__device__ __forceinline__ float tanhfast(float x) { return 1.f - 2.f / (__expf(2.f * x) + 1.f); }
__device__ __forceinline__ float bf2f(u16 h) {
    union { unsigned u; float f; } v; v.u = ((unsigned)h) << 16; return v.f;
}
__device__ __forceinline__ u16 f2bf(float f) {   // round-to-nearest-even
    union { float f; unsigned u; } v; v.f = f;
    unsigned r = v.u + 0x7fffu + ((v.u >> 16) & 1u);
    return (u16)(r >> 16);
}
#define MFMA(a, b, c) __builtin_amdgcn_mfma_f32_16x16x32_bf16(a, b, c, 0, 0, 0)

// ---------------------------------------------------------------------------
// fp32 -> bf16 casts
// ---------------------------------------------------------------------------
__global__ void k_cast(const float* __restrict__ s, u16* __restrict__ d, int n) {
    int i = blockIdx.x * 256 + threadIdx.x;
    if (i < n) d[i] = f2bf(s[i]);
}
// cwih (768,320) -> cond part (768,64) bf16
__global__ void k_cast_cwc(const float* __restrict__ cwih, u16* __restrict__ d) {
    int i = blockIdx.x * 256 + threadIdx.x;
    if (i < 768 * 64) { int r = i >> 6, c = i & 63; d[i] = f2bf(cwih[r * 320 + c]); }
}

// ---------------------------------------------------------------------------
// Per-token input projections (bf16 tables, biases folded in)
// ---------------------------------------------------------------------------
__global__ __launch_bounds__(256) void k_tok_gi(
    const float* __restrict__ embed,
    const float* __restrict__ gwih_f, const float* __restrict__ gbih_f,
    const float* __restrict__ gwih_b, const float* __restrict__ gbih_b,
    const float* __restrict__ cwih,   const float* __restrict__ cbih,
    u16* __restrict__ gif, u16* __restrict__ gib, u16* __restrict__ gic)
{
    int v = blockIdx.x, tid = threadIdx.x;
    __shared__ float es[256];
    es[tid] = embed[v * HH + tid];
    __syncthreads();
    for (int g = 0; g < 3; ++g) {
        int col = g * 256 + tid;
        float af = gbih_f[col], abv = gbih_b[col], ac = cbih[col];
        const float* wf = gwih_f + (size_t)col * HH;
        const float* wb = gwih_b + (size_t)col * HH;
        const float* wc = cwih   + (size_t)col * (HH + CONDD) + CONDD;
        for (int c = 0; c < 256; ++c) {
            float e = es[c];
            af += e * wf[c]; abv += e * wb[c]; ac += e * wc[c];
        }
        gif[v * H3 + col] = f2bf(af);
        gib[v * H3 + col] = f2bf(abv);
        gic[v * H3 + col] = f2bf(ac);
    }
}

// ---------------------------------------------------------------------------
// w-trajectory + out[.,.,0..2]
// ---------------------------------------------------------------------------
__global__ void k_wtraj(const int* __restrict__ actions, const int* __restrict__ w0,
                        float* __restrict__ out, int* __restrict__ w_used)
{
    int n = threadIdx.x;
    int w = w0[n];
    for (int t = 0; t < TT; ++t) {
        int A = actions[((size_t)t * NN + n) * 2 + 0];
        int W = actions[((size_t)t * NN + n) * 2 + 1];
        w_used[t * NN + n] = w;
        int wn = w + W - NLL;
        wn = wn < 0 ? 0 : (wn > NLL - 1 ? NLL - 1 : wn);
        float* o = out + ((size_t)t * NN + n) * OW;
        o[0] = (float)A; o[1] = (float)W; o[2] = (float)wn;
        w = wn;
    }
}

// ---------------------------------------------------------------------------
// MEGA persistent kernel.
//   bid < 256 : GRU role. 32 rows/block (block entirely fwd or bwd). 16 steps.
//               h kept in LDS (bf16 for MFMA A-frags, fp32 tile for B-proj).
//   bid >= 256: controller role (16 blocks x 16 batch rows). 32 steps.
//               gh = h@cwhh^T (K=256) + cond@cwihc^T (K=64) fused in MFMA acc;
//               n-gate cond part kept in separate acc (r-gating only scales gh).
// MFMA frag convention (k-permutation consistent across A and B):
//   A: m=lane&15, k elems = ks*32 + (lane>>4)*8 + e  (16B contiguous load)
//   B: n=lane&15, same k elems; B[k][n] = Wrowmajor[n][k] -> 16B contiguous
//   C: col=lane&15, row=(lane>>4)*4+reg   (m89-verified)
// ---------------------------------------------------------------------------
__global__ __launch_bounds__(512) void k_mega(
    const u16* __restrict__ whhbf_f, const u16* __restrict__ whhbf_b,
    const u16* __restrict__ gif, const u16* __restrict__ gib,
    const float* __restrict__ gbhh_f, const float* __restrict__ gbhh_b,
    const float* __restrict__ w2, const float* __restrict__ b2,
    float* __restrict__ Bf, float* __restrict__ Bb,
    const int* __restrict__ lines,
    const u16* __restrict__ cwhhbf, const u16* __restrict__ cwcbf,
    const u16* __restrict__ condbf, const u16* __restrict__ gic,
    const float* __restrict__ cbhh, const float* __restrict__ h0,
    const int* __restrict__ w_used,
    u16* __restrict__ Hallbf, float* __restrict__ out)
{
    __shared__ __align__(16) char smem[51968];
    const int bid  = blockIdx.x;
    const int tid  = threadIdx.x;
    const int lane = tid & 63;
    const int lm   = lane & 15, lg = lane >> 4;

    if (bid < 256) {
        // ---------------- GRU role ----------------
        u16*   hbf  = (u16*)smem;                       // [32][264] bf16
        float* hf32 = (float*)(smem + 16896);           // [32][258] f32
        int*   lns  = (int*)(smem + 16896 + 33024);     // [32][16]
        const int dir = bid >> 7;
        const int lb  = bid & 127;
        const int ii  = lb >> 3;
        const int nb  = (lb & 7) * 32;
        const u16*   whh  = dir ? whhbf_b : whhbf_f;
        const u16*   git  = dir ? gib : gif;
        const float* bhh  = dir ? gbhh_b : gbhh_f;
        float*       Bout = dir ? Bb : Bf;
        const int w = tid >> 6;   // wave 0..7, owns cols w*32..w*32+31 per chunk

        for (int k = tid; k < 32 * 264; k += 512) hbf[k] = 0;
        { int r = tid >> 4, c = tid & 15; lns[r * 16 + c] = lines[(nb + r) * 16 + c]; }
        __syncthreads();

        for (int s = 0; s < 16; ++s) {
            const int jpos = dir ? (15 - s) : s;
            f32x4 acc[3][2][2];
            #pragma unroll
            for (int q = 0; q < 3; ++q)
                #pragma unroll
                for (int c = 0; c < 2; ++c)
                    #pragma unroll
                    for (int r = 0; r < 2; ++r)
                        #pragma unroll
                        for (int z = 0; z < 4; ++z) acc[q][c][r][z] = 0.f;

            #pragma unroll
            for (int ks = 0; ks < 8; ++ks) {
                bf16x8 a0 = *(const bf16x8*)&hbf[lm * 264 + ks * 32 + lg * 8];
                bf16x8 a1 = *(const bf16x8*)&hbf[(16 + lm) * 264 + ks * 32 + lg * 8];
                #pragma unroll
                for (int q = 0; q < 3; ++q)
                    #pragma unroll
                    for (int cf = 0; cf < 2; ++cf) {
                        const u16* bp = whh + (size_t)(q * 256 + w * 32 + cf * 16 + lm) * 256
                                        + ks * 32 + lg * 8;
                        bf16x8 b = *(const bf16x8*)bp;
                        acc[q][cf][0] = MFMA(a0, b, acc[q][cf][0]);
                        acc[q][cf][1] = MFMA(a1, b, acc[q][cf][1]);
                    }
            }
            // gates -> hf32 tile
            #pragma unroll
            for (int cf = 0; cf < 2; ++cf) {
                int col = w * 32 + cf * 16 + lm;
                float br = bhh[col], bz = bhh[col + 256], bn = bhh[col + 512];
                #pragma unroll
                for (int rf = 0; rf < 2; ++rf)
                    #pragma unroll
                    for (int j = 0; j < 4; ++j) {
                        int lrow = rf * 16 + lg * 4 + j;
                        int tok  = lns[lrow * 16 + ((ii + jpos) & 15)];
                        const u16* gi = git + (size_t)tok * H3;
                        float ho = bf2f(hbf[lrow * 264 + col]);
                        float rg = sigm(bf2f(gi[col])       + acc[0][cf][rf][j] + br);
                        float zg = sigm(bf2f(gi[col + 256]) + acc[1][cf][rf][j] + bz);
                        float ng = tanhfast(bf2f(gi[col + 512]) + rg * (acc[2][cf][rf][j] + bn));
                        hf32[lrow * 258 + col] = (1.f - zg) * ng + zg * ho;
                    }
            }
            __syncthreads();
            // hbf <- bf16(hf32)
            {
                int lrow = tid >> 4, c0 = (tid & 15) * 16;
                u16 tmp[16];
                #pragma unroll
                for (int k = 0; k < 16; ++k) tmp[k] = f2bf(hf32[lrow * 258 + c0 + k]);
                *(uint4*)&hbf[lrow * 264 + c0]     = *(uint4*)&tmp[0];
                *(uint4*)&hbf[lrow * 264 + c0 + 8] = *(uint4*)&tmp[8];
            }
            // fused B projection (fp32 h)
            if (tid < 256) {
                int r = tid >> 3, e = tid & 7;
                float a = b2[e];
                const float* w2r = w2 + e * 256;
                for (int c = 0; c < 256; ++c) a += hf32[r * 258 + c] * w2r[c];
                int grow = ii * 256 + nb + r;
                Bout[((size_t)grow * NLL + jpos) * NEE + e] = sigm(a);
            }
            __syncthreads();
        }
    } else {
        // ---------------- controller role ----------------
        u16* hc = (u16*)smem;            // [16][264] bf16
        const int cb = bid - 256;        // 0..15, rows cb*16..cb*16+15
        if (tid < 256) {
            int lrow = tid >> 4, c0 = (tid & 15) * 16;
            u16 tmp[16];
            #pragma unroll
            for (int k = 0; k < 16; ++k)
                tmp[k] = f2bf(h0[(size_t)(cb * 16 + lrow) * 256 + c0 + k]);
            *(uint4*)&hc[lrow * 264 + c0]     = *(uint4*)&tmp[0];
            *(uint4*)&hc[lrow * 264 + c0 + 8] = *(uint4*)&tmp[8];
        }
        __syncthreads();
        const int w = tid >> 6;  // 0..3 for active threads

        for (int t = 0; t < TT; ++t) {
            f32x4 accM[3][4], accC[4];
            if (tid < 256) {
                #pragma unroll
                for (int q = 0; q < 3; ++q)
                    #pragma unroll
                    for (int c = 0; c < 4; ++c)
                        #pragma unroll
                        for (int z = 0; z < 4; ++z) accM[q][c][z] = 0.f;
                #pragma unroll
                for (int c = 0; c < 4; ++c)
                    #pragma unroll
                    for (int z = 0; z < 4; ++z) accC[c][z] = 0.f;

                // h @ cwhh^T  (K=256)
                #pragma unroll
                for (int ks = 0; ks < 8; ++ks) {
                    bf16x8 a = *(const bf16x8*)&hc[lm * 264 + ks * 32 + lg * 8];
                    #pragma unroll
                    for (int q = 0; q < 3; ++q)
                        #pragma unroll
                        for (int cf = 0; cf < 4; ++cf) {
                            const u16* bp = cwhhbf + (size_t)(q * 256 + w * 64 + cf * 16 + lm) * 256
                                            + ks * 32 + lg * 8;
                            accM[q][cf] = MFMA(a, *(const bf16x8*)bp, accM[q][cf]);
                        }
                }
                // cond @ cwih_cond^T  (K=64); chunks r,z merge; n-chunk separate
                #pragma unroll
                for (int ks = 0; ks < 2; ++ks) {
                    bf16x8 a = *(const bf16x8*)&condbf[(size_t)(t * 256 + cb * 16 + lm) * 64
                                                       + ks * 32 + lg * 8];
                    #pragma unroll
                    for (int q = 0; q < 3; ++q)
                        #pragma unroll
                        for (int cf = 0; cf < 4; ++cf) {
                            const u16* bp = cwcbf + (size_t)(q * 256 + w * 64 + cf * 16 + lm) * 64
                                            + ks * 32 + lg * 8;
                            bf16x8 b = *(const bf16x8*)bp;
                            if (q < 2) accM[q][cf] = MFMA(a, b, accM[q][cf]);
                            else       accC[cf]    = MFMA(a, b, accC[cf]);
                        }
                }
            }
            __syncthreads();   // all hc reads complete
            if (tid < 256) {
                #pragma unroll
                for (int cf = 0; cf < 4; ++cf) {
                    int col = w * 64 + cf * 16 + lm;
                    float br = cbhh[col], bz = cbhh[col + 256], bn = cbhh[col + 512];
                    #pragma unroll
                    for (int j = 0; j < 4; ++j) {
                        int lrow = lg * 4 + j;
                        int n = cb * 16 + lrow;
                        int wv = w_used[t * 256 + n];
                        int tok = lines[n * 16 + wv];
                        const u16* gi = gic + (size_t)tok * H3;
                        float ho = bf2f(hc[lrow * 264 + col]);
                        float rg = sigm(bf2f(gi[col])       + accM[0][cf][j] + br);
                        float zg = sigm(bf2f(gi[col + 256]) + accM[1][cf][j] + bz);
                        float ng = tanhfast(bf2f(gi[col + 512]) + accC[cf][j]
                                            + rg * (accM[2][cf][j] + bn));
                        float hn = (1.f - zg) * ng + zg * ho;
                        out[((size_t)t * 256 + n) * OW + 4 + col] = hn;
                        Hallbf[((size_t)t * 256 + n) * 256 + col] = f2bf(hn);
                        hc[lrow * 264 + col] = f2bf(hn);   // same-element RAW: own read done
                    }
                }
            }
            __syncthreads();   // hc ready for next step
        }
    }
}

// ---------------------------------------------------------------------------
// Stick-breaking + reversals + roll into final P layout (unchanged, verified)
// ---------------------------------------------------------------------------
__global__ __launch_bounds__(256) void k_stick(
    const float* __restrict__ Bf, const float* __restrict__ Bb,
    float* __restrict__ P_final)
{
    int idx = blockIdx.x * 256 + threadIdx.x;
    if (idx >= 16 * 256 * 8) return;
    int e = idx & 7, n = (idx >> 3) & 255, i = idx >> 11;
    const float* bf = Bf + ((size_t)(i * NN + n) * NLL) * NEE + e;
    const float* bb = Bb + ((size_t)(i * NN + n) * NLL) * NEE + e;
    int i2 = (i + 15) & 15;
    float* dst = P_final + ((size_t)(i2 * NN + n) * 32) * NEE + e;
    float cum = 1.f;
    #pragma unroll
    for (int m = 0; m < 16; ++m) {
        float c0 = bf[m * NEE];
        float c1 = bb[(15 - m) * NEE];
        float v0 = c0 * cum;
        cum *= (1.f - c0);
        float v1 = (m < 15) ? c1 * cum : cum;
        cum *= (1.f - c1);
        dst[(size_t)(((17 + m) & 31)) * NEE] = v0;
        dst[(size_t)((16 - m)) * NEE]        = v1;
    }
}

// ---------------------------------------------------------------------------
// Batched MLP layer: Out = bf16(relu(A @ W^T + bias)), A (8192,256) bf16
// ---------------------------------------------------------------------------
__global__ __launch_bounds__(256) void k_mlp(
    const u16* __restrict__ A, const u16* __restrict__ W,
    const float* __restrict__ bias, u16* __restrict__ Out)
{
    __shared__ u16 ot[32 * 264];
    const int g0 = blockIdx.x * 32;
    const int tid = threadIdx.x, lane = tid & 63, w = tid >> 6;
    const int lm = lane & 15, lg = lane >> 4;
    f32x4 acc[4][2];
    #pragma unroll
    for (int c = 0; c < 4; ++c)
        #pragma unroll
        for (int r = 0; r < 2; ++r)
            #pragma unroll
            for (int z = 0; z < 4; ++z) acc[c][r][z] = 0.f;
    #pragma unroll
    for (int ks = 0; ks < 8; ++ks) {
        bf16x8 a0 = *(const bf16x8*)&A[(size_t)(g0 + lm) * 256 + ks * 32 + lg * 8];
        bf16x8 a1 = *(const bf16x8*)&A[(size_t)(g0 + 16 + lm) * 256 + ks * 32 + lg * 8];
        #pragma unroll
        for (int cf = 0; cf < 4; ++cf) {
            const u16* bp = W + (size_t)(w * 64 + cf * 16 + lm) * 256 + ks * 32 + lg * 8;
            bf16x8 b = *(const bf16x8*)bp;
            acc[cf][0] = MFMA(a0, b, acc[cf][0]);
            acc[cf][1] = MFMA(a1, b, acc[cf][1]);
        }
    }
    #pragma unroll
    for (int cf = 0; cf < 4; ++cf) {
        int col = w * 64 + cf * 16 + lm;
        float bs = bias[col];
        #pragma unroll
        for (int rf = 0; rf < 2; ++rf)
            #pragma unroll
            for (int j = 0; j < 4; ++j) {
                int lrow = rf * 16 + lg * 4 + j;
                ot[lrow * 264 + col] = f2bf(fmaxf(acc[cf][rf][j] + bs, 0.f));
            }
    }
    __syncthreads();
    int lrow = tid >> 3, c0 = (tid & 7) * 32;
    const uint4* src = (const uint4*)&ot[lrow * 264 + c0];
    uint4* dst = (uint4*)&Out[(size_t)(g0 + lrow) * 256 + c0];
    dst[0] = src[0]; dst[1] = src[1]; dst[2] = src[2]; dst[3] = src[3];
}

// ---------------------------------------------------------------------------
// Heads: 25 logits per row + softmaxes + v + p_probs, writes out cols 3,260..307
// ---------------------------------------------------------------------------
__global__ __launch_bounds__(256) void k_heads(
    const u16* __restrict__ zbf,
    const float* __restrict__ aw, const float* __restrict__ ab,
    const float* __restrict__ ow, const float* __restrict__ ob,
    const float* __restrict__ cw, const float* __restrict__ cb,
    const float* __restrict__ P_final, const int* __restrict__ w_used,
    float* __restrict__ out)
{
    __shared__ float zt[32 * 258];
    __shared__ float hd[32][28];
    __shared__ float o8[32][8];
    __shared__ int   wv[32];
    const int g0 = blockIdx.x * 32, tid = threadIdx.x;
    {
        int lrow = tid >> 3, c0 = (tid & 7) * 32;
        const u16* src = &zbf[(size_t)(g0 + lrow) * 256 + c0];
        #pragma unroll
        for (int k = 0; k < 32; ++k) zt[lrow * 258 + c0 + k] = bf2f(src[k]);
    }
    if (tid < 32) wv[tid] = w_used[g0 + tid];
    __syncthreads();
    {
        int r = tid >> 3, s = tid & 7;
        const float* z = &zt[r * 258];
        float a1 = ab[s], a2 = ab[8 + s], a3 = ob[s], a4 = cb[0];
        const float* w1 = aw + s * 256;
        const float* w2_ = aw + (8 + s) * 256;
        const float* w3 = ow + s * 256;
        for (int c = 0; c < 256; ++c) {
            float zv = z[c];
            a1 += zv * w1[c]; a2 += zv * w2_[c]; a3 += zv * w3[c]; a4 += zv * cw[c];
        }
        hd[r][s] = a1; hd[r][8 + s] = a2; hd[r][16 + s] = a3;
        if (s == 0) hd[r][24] = a4;
    }
    __syncthreads();
    if (tid < 32) {
        int r = tid; int g = g0 + r;
        float* orow = out + (size_t)g * OW;
        float mx = hd[r][0];
        #pragma unroll
        for (int k = 1; k < 16; ++k) mx = fmaxf(mx, hd[r][k]);
        float ex[16], ssum = 0.f;
        #pragma unroll
        for (int k = 0; k < 16; ++k) { ex[k] = __expf(hd[r][k] - mx); ssum += ex[k]; }
        float inv = 1.f / ssum;
        #pragma unroll
        for (int k = 0; k < 16; ++k) orow[260 + k] = ex[k] * inv;
        orow[3] = hd[r][24];
        float mo = hd[r][16];
        #pragma unroll
        for (int k = 1; k < 8; ++k) mo = fmaxf(mo, hd[r][16 + k]);
        float eo[8], so = 0.f;
        #pragma unroll
        for (int k = 0; k < 8; ++k) { eo[k] = __expf(hd[r][16 + k] - mo); so += eo[k]; }
        float invo = 1.f / so;
        #pragma unroll
        for (int k = 0; k < 8; ++k) o8[r][k] = eo[k] * invo;
    }
    __syncthreads();
    {
        int r = tid >> 3, kb = tid & 7;
        int g = g0 + r, n = g & 255;
        const float* base = P_final + ((size_t)(wv[r] * NN + n) * 32) * NEE;
        float* orow = out + (size_t)g * OW + 276;
        #pragma unroll
        for (int m = 0; m < 4; ++m) {
            int k = kb + m * 8;
            const float* pe = base + k * NEE;
            float a = 0.f;
            #pragma unroll
            for (int e = 0; e < 8; ++e) a += pe[e] * o8[r][e];
            orow[k] = a;
        }
    }
}

// ---------------------------------------------------------------------------
extern "C" void kernel_launch(void* const* d_in, const int* in_sizes, int n_in,
                              void* d_out, int out_size, void* d_ws, size_t ws_size,
                              hipStream_t stream) {
    const float* condition = (const float*)d_in[0];
    const int*   lines     = (const int*)  d_in[1];
    const int*   actions   = (const int*)  d_in[2];
    const float* h0        = (const float*)d_in[3];
    const int*   w0        = (const int*)  d_in[4];
    const float* embed     = (const float*)d_in[5];
    const float* gwih_f    = (const float*)d_in[6];
    const float* gwhh_f    = (const float*)d_in[7];
    const float* gbih_f    = (const float*)d_in[8];
    const float* gbhh_f    = (const float*)d_in[9];
    const float* gwih_b    = (const float*)d_in[10];
    const float* gwhh_b    = (const float*)d_in[11];
    const float* gbih_b    = (const float*)d_in[12];
    const float* gbhh_b    = (const float*)d_in[13];
    const float* w2        = (const float*)d_in[14];
    const float* b2        = (const float*)d_in[15];
    const float* cwih      = (const float*)d_in[16];
    const float* cwhh      = (const float*)d_in[17];
    const float* cbih      = (const float*)d_in[18];
    const float* cbhh      = (const float*)d_in[19];
    const float* mw1       = (const float*)d_in[20];
    const float* mb1       = (const float*)d_in[21];
    const float* mw2       = (const float*)d_in[22];
    const float* mb2       = (const float*)d_in[23];
    const float* ow        = (const float*)d_in[24];
    const float* ob        = (const float*)d_in[25];
    const float* aw        = (const float*)d_in[26];
    const float* ab        = (const float*)d_in[27];
    const float* cw        = (const float*)d_in[28];
    const float* cb        = (const float*)d_in[29];
    float* out = (float*)d_out;

    // workspace carve-up (~19.3 MB peak, aliased)
    char* base = (char*)d_ws;
    auto alloc = [&](size_t bytes) { char* r = base; base += (bytes + 255) & ~(size_t)255; return r; };
    u16*   gif_tok = (u16*)alloc(64 * H3 * 2);
    u16*   gib_tok = (u16*)alloc(64 * H3 * 2);
    u16*   gic_tok = (u16*)alloc(64 * H3 * 2);
    u16*   whhbf_f = (u16*)alloc(H3 * 256 * 2);
    u16*   whhbf_b = (u16*)alloc(H3 * 256 * 2);
    u16*   cwhhbf  = (u16*)alloc(H3 * 256 * 2);
    u16*   mw1bf   = (u16*)alloc(256 * 256 * 2);
    u16*   mw2bf   = (u16*)alloc(256 * 256 * 2);
    u16*   cwcbf   = (u16*)alloc(H3 * 64 * 2);
    u16*   condbf  = (u16*)alloc((size_t)TT * NN * CONDD * 2);
    float* Bf      = (float*)alloc((size_t)16 * 256 * 16 * 8 * 4);   // aliased: z1bf
    float* Bb      = (float*)alloc((size_t)16 * 256 * 16 * 8 * 4);   // (contiguous w/ Bf)
    float* P_final = (float*)alloc((size_t)16 * 256 * 32 * 8 * 4);
    u16*   Hallbf  = (u16*)alloc((size_t)TT * NN * 256 * 2);
    u16*   zbf     = (u16*)alloc((size_t)TT * NN * 256 * 2);
    int*   w_used  = (int*)alloc((size_t)TT * NN * 4);
    u16*   z1bf    = (u16*)Bf;   // reuse Bf+Bb (4 MB) after k_stick

    // bf16 weight/activation conversions
    k_cast<<<(196608 + 255) / 256, 256, 0, stream>>>(gwhh_f, whhbf_f, 196608);
    k_cast<<<(196608 + 255) / 256, 256, 0, stream>>>(gwhh_b, whhbf_b, 196608);
    k_cast<<<(196608 + 255) / 256, 256, 0, stream>>>(cwhh, cwhhbf, 196608);
    k_cast<<<(65536 + 255) / 256, 256, 0, stream>>>(mw1, mw1bf, 65536);
    k_cast<<<(65536 + 255) / 256, 256, 0, stream>>>(mw2, mw2bf, 65536);
    k_cast<<<(524288 + 255) / 256, 256, 0, stream>>>(condition, condbf, 524288);
    k_cast_cwc<<<192, 256, 0, stream>>>(cwih, cwcbf);

    k_tok_gi<<<64, 256, 0, stream>>>(embed, gwih_f, gbih_f, gwih_b, gbih_b, cwih, cbih,
                                     gif_tok, gib_tok, gic_tok);
    k_wtraj<<<1, 256, 0, stream>>>(actions, w0, out, w_used);

    // GRU (256 blocks) + controller (16 blocks), persistent, concurrent
    k_mega<<<272, 512, 0, stream>>>(whhbf_f, whhbf_b, gif_tok, gib_tok, gbhh_f, gbhh_b,
                                    w2, b2, Bf, Bb, lines,
                                    cwhhbf, cwcbf, condbf, gic_tok, cbhh, h0, w_used,
                                    Hallbf, out);

    k_stick<<<128, 256, 0, stream>>>(Bf, Bb, P_final);

    k_mlp<<<256, 256, 0, stream>>>(Hallbf, mw1bf, mb1, z1bf);
    k_mlp<<<256, 256, 0, stream>>>(z1bf, mw2bf, mb2, zbf);

    k_heads<<<256, 256, 0, stream>>>(zbf, aw, ab, ow, ob, cw, cb, P_final, w_used, out);
}